// Round 9
// baseline (429.407 us; speedup 1.0000x reference)
//
#include <hip/hip_runtime.h>

// GCN: out = relu(segment_sum(feat[src], dst) @ W.T + b)
// Round 9: keep chain build (measured 140us, cheaper than CSR's 260us).
// Gather was miss-bound (FETCH 272MB: ~100MB nodes lines + ~180MB feat lines).
//   + k_cast_bf16: feat -> bf16 (RNE) in ws. Halves feat miss bytes, doubles
//     cache residency.
//   + k_gather2_chain_linear: TWO independent chains per wave (2x MLP against
//     chain-chase latency), bf16 feat reads, fused in-register linear + relu.
// Fallback to atomic-scatter path if ws too small.

__device__ __forceinline__ float bcast_lane(float x, int k) {
    return __uint_as_float(__builtin_amdgcn_readlane(__float_as_uint(x), k));
}
__device__ __forceinline__ float bf16_to_f32(unsigned short h) {
    return __uint_as_float(((unsigned int)h) << 16);
}
__device__ __forceinline__ unsigned short f32_to_bf16_rne(float f) {
    unsigned int x = __float_as_uint(f);
    unsigned int r = x + 0x7fffu + ((x >> 16) & 1u);
    return (unsigned short)(r >> 16);
}

// ---------------- feat -> bf16 cast ----------------

__global__ void k_cast_bf16(const float* __restrict__ feat,
                            unsigned short* __restrict__ featB, int total4) {
    int i = blockIdx.x * blockDim.x + threadIdx.x;
    if (i < total4) {
        float4 v = ((const float4*)feat)[i];
        ushort4 o;
        o.x = f32_to_bf16_rne(v.x);
        o.y = f32_to_bf16_rne(v.y);
        o.z = f32_to_bf16_rne(v.z);
        o.w = f32_to_bf16_rne(v.w);
        ((ushort4*)featB)[i] = o;
    }
}

// ---------------- chain build ----------------

__global__ void k_build_chains(const int* __restrict__ src,
                               const int* __restrict__ dst,
                               int* __restrict__ head,
                               int2* __restrict__ nodes, int E) {
    int e = blockIdx.x * blockDim.x + threadIdx.x;
    if (e < E) {
        int d = dst[e];
        int s = src[e];
        int prev = atomicExch(&head[d], e);   // random 4B RMW in 400KB (L2)
        nodes[e] = make_int2(prev, s);        // coalesced 8B store
    }
}

// ---------------- fused 2-chain gather + linear + relu ----------------
// wave handles nodes n0=2p, n1=2p+1 simultaneously (two independent chains ->
// two dependency streams in flight). lane = feature. Linear fused via
// readlane broadcast against W row held per lane.

__global__ void k_gather2_chain_linear(const unsigned short* __restrict__ featB,
                                       const float* __restrict__ W,
                                       const float* __restrict__ b,
                                       const int* __restrict__ head,
                                       const int2* __restrict__ nodes,
                                       float* __restrict__ out, int N) {
    int lane = threadIdx.x & 63;
    int wid = (blockIdx.x * blockDim.x + threadIdx.x) >> 6;
    int nw = (gridDim.x * blockDim.x) >> 6;

    float4 w[16];
    const float4* Wv = (const float4*)(W + (lane << 6));
    #pragma unroll
    for (int q = 0; q < 16; ++q) w[q] = Wv[q];
    float bj = b[lane];

    for (int p = wid; (p << 1) < N; p += nw) {
        int n0 = p << 1;
        int n1 = n0 + 1;
        float s0 = 0.0f, s1 = 0.0f;
        int e0 = head[n0];
        int e1 = (n1 < N) ? head[n1] : -1;

        while (e0 >= 0 || e1 >= 0) {
            if (e0 >= 0) {
                int2 a = nodes[e0];
                s0 += bf16_to_f32(featB[(a.y << 6) + lane]);
                e0 = a.x;
            }
            if (e1 >= 0) {
                int2 a = nodes[e1];
                s1 += bf16_to_f32(featB[(a.y << 6) + lane]);
                e1 = a.x;
            }
        }

        float acc0 = bj, acc1 = bj;
        #pragma unroll
        for (int k = 0; k < 64; ++k) {
            float wk = ((const float*)w)[k];
            acc0 = fmaf(bcast_lane(s0, k), wk, acc0);
            acc1 = fmaf(bcast_lane(s1, k), wk, acc1);
        }
        out[(n0 << 6) + lane] = fmaxf(acc0, 0.0f);
        if (n1 < N) out[(n1 << 6) + lane] = fmaxf(acc1, 0.0f);
    }
}

// ---------------- fallback: atomic path ----------------

__global__ void gcn_scatter_kernel(const float* __restrict__ feat,
                                   const int* __restrict__ src,
                                   const int* __restrict__ dst,
                                   float* __restrict__ agg,
                                   int n_edges) {
    long long tid = (long long)blockIdx.x * blockDim.x + threadIdx.x;
    int e = (int)(tid >> 6);
    int f = (int)(tid & 63);
    if (e >= n_edges) return;
    atomicAdd(&agg[(long long)dst[e] * 64 + f], feat[(long long)src[e] * 64 + f]);
}

__global__ void gcn_linear_relu_kernel(const float* __restrict__ agg,
                                       const float* __restrict__ W,
                                       const float* __restrict__ b,
                                       float* __restrict__ out,
                                       int n_nodes) {
    __shared__ float Wt[64 * 65];
    __shared__ float bs[64];
    __shared__ float rows[4 * 64];
    int tid = threadIdx.x;
    #pragma unroll
    for (int it = 0; it < 16; ++it) {
        int idx = it * 256 + tid;
        Wt[(idx & 63) * 65 + (idx >> 6)] = W[idx];
    }
    if (tid < 64) bs[tid] = b[tid];
    __syncthreads();
    int li = tid >> 6, j = tid & 63;
    for (int r0 = blockIdx.x * 4; r0 < n_nodes; r0 += gridDim.x * 4) {
        int n = r0 + li;
        __syncthreads();
        if (n < n_nodes) rows[tid] = agg[(long long)n * 64 + j];
        __syncthreads();
        if (n < n_nodes) {
            float sum = bs[j];
            #pragma unroll
            for (int k = 0; k < 64; ++k)
                sum += rows[li * 64 + k] * Wt[k * 65 + j];
            out[(long long)n * 64 + j] = fmaxf(sum, 0.0f);
        }
    }
}

extern "C" void kernel_launch(void* const* d_in, const int* in_sizes, int n_in,
                              void* d_out, int out_size, void* d_ws, size_t ws_size,
                              hipStream_t stream) {
    const float* feat = (const float*)d_in[0];
    const float* W    = (const float*)d_in[1];
    const float* b    = (const float*)d_in[2];
    const int*   src  = (const int*)d_in[3];
    const int*   dst  = (const int*)d_in[4];
    float* out = (float*)d_out;

    int N = in_sizes[0] / 64;
    int E = in_sizes[3];

    // ws layout: featB[N*64] ushort | head[N] int | nodes[E] int2
    size_t featB_bytes = (size_t)N * 64 * sizeof(unsigned short);   // 12.8 MB
    size_t head_bytes  = (size_t)N * sizeof(int);                   // 0.4 MB
    size_t nodes_bytes = (size_t)E * sizeof(int2);                  // 12.8 MB
    size_t need = featB_bytes + head_bytes + nodes_bytes;           // ~26 MB

    if (ws_size >= need) {
        unsigned short* featB = (unsigned short*)d_ws;
        int*  head  = (int*)((char*)d_ws + featB_bytes);
        int2* nodes = (int2*)((char*)d_ws + featB_bytes + head_bytes);

        int total4 = N * 16;   // N*64/4 float4 groups
        k_cast_bf16<<<(total4 + 255) / 256, 256, 0, stream>>>(feat, featB, total4);

        hipMemsetAsync(head, 0xFF, head_bytes, stream);   // all -1

        k_build_chains<<<(E + 255) / 256, 256, 0, stream>>>(src, dst, head, nodes, E);

        k_gather2_chain_linear<<<2048, 256, 0, stream>>>(featB, W, b, head, nodes, out, N);
    } else {
        // fallback: atomic scatter into out (in-place-safe linear)
        float* agg = out;
        hipMemsetAsync(agg, 0, (size_t)N * 64 * sizeof(float), stream);
        long long total = (long long)E * 64;
        gcn_scatter_kernel<<<(int)((total + 255) / 256), 256, 0, stream>>>(feat, src, dst, agg, E);
        gcn_linear_relu_kernel<<<1280, 256, 0, stream>>>(agg, W, b, out, N);
    }
}

// Round 11
// 279.833 us; speedup vs baseline: 1.5345x; 1.5345x over previous
//
#include <hip/hip_runtime.h>

// GCN: out = relu(segment_sum(feat[src], dst) @ W.T + b)
// Round 10/11 (resubmit after infra timeout; never measured): r9 regressed
// (280us gather, VALU 16%) because the 2-chain loop's if-branches serialized
// the dependent loads. Fix: 4 chains per wave, branch-free cndmask bodies,
// software-pipelined (4 feat + 4 node loads in flight). Finished chains spin
// on hot cached lines (no traffic). bf16 feat kept (traffic halving
// confirmed: FETCH 272->173MB). f32 accumulation.
// Build unchanged: cast + memset + lock-free chain build (~140us).

__device__ __forceinline__ float bcast_lane(float x, int k) {
    return __uint_as_float(__builtin_amdgcn_readlane(__float_as_uint(x), k));
}
__device__ __forceinline__ float bf16_to_f32(unsigned short h) {
    return __uint_as_float(((unsigned int)h) << 16);
}
__device__ __forceinline__ unsigned short f32_to_bf16_rne(float f) {
    unsigned int x = __float_as_uint(f);
    unsigned int r = x + 0x7fffu + ((x >> 16) & 1u);
    return (unsigned short)(r >> 16);
}

// ---------------- feat -> bf16 cast ----------------

__global__ void k_cast_bf16(const float* __restrict__ feat,
                            unsigned short* __restrict__ featB, int total4) {
    int i = blockIdx.x * blockDim.x + threadIdx.x;
    if (i < total4) {
        float4 v = ((const float4*)feat)[i];
        ushort4 o;
        o.x = f32_to_bf16_rne(v.x);
        o.y = f32_to_bf16_rne(v.y);
        o.z = f32_to_bf16_rne(v.z);
        o.w = f32_to_bf16_rne(v.w);
        ((ushort4*)featB)[i] = o;
    }
}

// ---------------- chain build ----------------

__global__ void k_build_chains(const int* __restrict__ src,
                               const int* __restrict__ dst,
                               int* __restrict__ head,
                               int2* __restrict__ nodes, int E) {
    int e = blockIdx.x * blockDim.x + threadIdx.x;
    if (e < E) {
        int d = dst[e];
        int s = src[e];
        int prev = atomicExch(&head[d], e);   // random 4B RMW in 400KB (L2)
        nodes[e] = make_int2(prev, s);        // coalesced 8B store
    }
}

// ---------------- fused 4-chain gather + linear + relu ----------------
// Wave owns nodes 4p..4p+3 (4 independent chains). Loop body is straight-line:
// clamp dead chains to edge 0 (hot line), select contributions with cndmask.
// Pipelined: current iteration's 4 feat loads overlap the 4 next-node loads.

__global__ void __launch_bounds__(256)
k_gather4_chain_linear(const unsigned short* __restrict__ featB,
                       const float* __restrict__ W,
                       const float* __restrict__ b,
                       const int* __restrict__ head,
                       const int2* __restrict__ nodes,
                       float* __restrict__ out, int N) {
    int lane = threadIdx.x & 63;
    int wid = (blockIdx.x * blockDim.x + threadIdx.x) >> 6;
    int nw = (gridDim.x * blockDim.x) >> 6;

    float4 w[16];
    const float4* Wv = (const float4*)(W + (lane << 6));
    #pragma unroll
    for (int q = 0; q < 16; ++q) w[q] = Wv[q];
    float bj = b[lane];

    for (int p = wid; (p << 2) < N; p += nw) {
        int n0 = p << 2;
        int e0 = head[n0];
        int e1 = (n0 + 1 < N) ? head[n0 + 1] : -1;
        int e2 = (n0 + 2 < N) ? head[n0 + 2] : -1;
        int e3 = (n0 + 3 < N) ? head[n0 + 3] : -1;
        float s0 = 0.f, s1 = 0.f, s2 = 0.f, s3 = 0.f;

        // prologue: node records for first step (dead chains read nodes[0])
        int2 a0 = nodes[e0 >= 0 ? e0 : 0];
        int2 a1 = nodes[e1 >= 0 ? e1 : 0];
        int2 a2 = nodes[e2 >= 0 ? e2 : 0];
        int2 a3 = nodes[e3 >= 0 ? e3 : 0];

        while ((e0 >= 0) || (e1 >= 0) || (e2 >= 0) || (e3 >= 0)) {
            // 4 independent feat-row loads (in flight together)
            unsigned short v0 = featB[(a0.y << 6) + lane];
            unsigned short v1 = featB[(a1.y << 6) + lane];
            unsigned short v2 = featB[(a2.y << 6) + lane];
            unsigned short v3 = featB[(a3.y << 6) + lane];

            // advance chain ids
            int f0 = (e0 >= 0) ? a0.x : -1;
            int f1 = (e1 >= 0) ? a1.x : -1;
            int f2 = (e2 >= 0) ? a2.x : -1;
            int f3 = (e3 >= 0) ? a3.x : -1;

            // next node records (overlap with v* consumption)
            int2 b0 = nodes[f0 >= 0 ? f0 : 0];
            int2 b1 = nodes[f1 >= 0 ? f1 : 0];
            int2 b2 = nodes[f2 >= 0 ? f2 : 0];
            int2 b3 = nodes[f3 >= 0 ? f3 : 0];

            s0 += (e0 >= 0) ? bf16_to_f32(v0) : 0.0f;
            s1 += (e1 >= 0) ? bf16_to_f32(v1) : 0.0f;
            s2 += (e2 >= 0) ? bf16_to_f32(v2) : 0.0f;
            s3 += (e3 >= 0) ? bf16_to_f32(v3) : 0.0f;

            e0 = f0; e1 = f1; e2 = f2; e3 = f3;
            a0 = b0; a1 = b1; a2 = b2; a3 = b3;
        }

        // fused linear + bias + relu for the 4 nodes
        float c0 = bj, c1 = bj, c2 = bj, c3 = bj;
        #pragma unroll
        for (int k = 0; k < 64; ++k) {
            float wk = ((const float*)w)[k];
            c0 = fmaf(bcast_lane(s0, k), wk, c0);
            c1 = fmaf(bcast_lane(s1, k), wk, c1);
            c2 = fmaf(bcast_lane(s2, k), wk, c2);
            c3 = fmaf(bcast_lane(s3, k), wk, c3);
        }
        out[(n0 << 6) + lane] = fmaxf(c0, 0.0f);
        if (n0 + 1 < N) out[((n0 + 1) << 6) + lane] = fmaxf(c1, 0.0f);
        if (n0 + 2 < N) out[((n0 + 2) << 6) + lane] = fmaxf(c2, 0.0f);
        if (n0 + 3 < N) out[((n0 + 3) << 6) + lane] = fmaxf(c3, 0.0f);
    }
}

// ---------------- fallback: atomic path ----------------

__global__ void gcn_scatter_kernel(const float* __restrict__ feat,
                                   const int* __restrict__ src,
                                   const int* __restrict__ dst,
                                   float* __restrict__ agg,
                                   int n_edges) {
    long long tid = (long long)blockIdx.x * blockDim.x + threadIdx.x;
    int e = (int)(tid >> 6);
    int f = (int)(tid & 63);
    if (e >= n_edges) return;
    atomicAdd(&agg[(long long)dst[e] * 64 + f], feat[(long long)src[e] * 64 + f]);
}

__global__ void gcn_linear_relu_kernel(const float* __restrict__ agg,
                                       const float* __restrict__ W,
                                       const float* __restrict__ b,
                                       float* __restrict__ out,
                                       int n_nodes) {
    __shared__ float Wt[64 * 65];
    __shared__ float bs[64];
    __shared__ float rows[4 * 64];
    int tid = threadIdx.x;
    #pragma unroll
    for (int it = 0; it < 16; ++it) {
        int idx = it * 256 + tid;
        Wt[(idx & 63) * 65 + (idx >> 6)] = W[idx];
    }
    if (tid < 64) bs[tid] = b[tid];
    __syncthreads();
    int li = tid >> 6, j = tid & 63;
    for (int r0 = blockIdx.x * 4; r0 < n_nodes; r0 += gridDim.x * 4) {
        int n = r0 + li;
        __syncthreads();
        if (n < n_nodes) rows[tid] = agg[(long long)n * 64 + j];
        __syncthreads();
        if (n < n_nodes) {
            float sum = bs[j];
            #pragma unroll
            for (int k = 0; k < 64; ++k)
                sum += rows[li * 64 + k] * Wt[k * 65 + j];
            out[(long long)n * 64 + j] = fmaxf(sum, 0.0f);
        }
    }
}

extern "C" void kernel_launch(void* const* d_in, const int* in_sizes, int n_in,
                              void* d_out, int out_size, void* d_ws, size_t ws_size,
                              hipStream_t stream) {
    const float* feat = (const float*)d_in[0];
    const float* W    = (const float*)d_in[1];
    const float* b    = (const float*)d_in[2];
    const int*   src  = (const int*)d_in[3];
    const int*   dst  = (const int*)d_in[4];
    float* out = (float*)d_out;

    int N = in_sizes[0] / 64;
    int E = in_sizes[3];

    // ws layout: featB[N*64] ushort | head[N] int | nodes[E] int2
    size_t featB_bytes = (size_t)N * 64 * sizeof(unsigned short);   // 12.8 MB
    size_t head_bytes  = (size_t)N * sizeof(int);                   // 0.4 MB
    size_t nodes_bytes = (size_t)E * sizeof(int2);                  // 12.8 MB
    size_t need = featB_bytes + head_bytes + nodes_bytes;           // ~26 MB

    if (ws_size >= need) {
        unsigned short* featB = (unsigned short*)d_ws;
        int*  head  = (int*)((char*)d_ws + featB_bytes);
        int2* nodes = (int2*)((char*)d_ws + featB_bytes + head_bytes);

        int total4 = N * 16;   // N*64/4 float4 groups
        k_cast_bf16<<<(total4 + 255) / 256, 256, 0, stream>>>(feat, featB, total4);

        hipMemsetAsync(head, 0xFF, head_bytes, stream);   // all -1

        k_build_chains<<<(E + 255) / 256, 256, 0, stream>>>(src, dst, head, nodes, E);

        k_gather4_chain_linear<<<2048, 256, 0, stream>>>(featB, W, b, head, nodes, out, N);
    } else {
        // fallback: atomic scatter into out (in-place-safe linear)
        float* agg = out;
        hipMemsetAsync(agg, 0, (size_t)N * 64 * sizeof(float), stream);
        long long total = (long long)E * 64;
        gcn_scatter_kernel<<<(int)((total + 255) / 256), 256, 0, stream>>>(feat, src, dst, agg, E);
        gcn_linear_relu_kernel<<<1280, 256, 0, stream>>>(agg, W, b, out, N);
    }
}